// Round 5
// baseline (945.068 us; speedup 1.0000x reference)
//
#include <hip/hip_runtime.h>
#include <math.h>

#define N_PTS  131072
#define K_DIM  16
#define D_BINS 1024

typedef float v2f __attribute__((ext_vector_type(2)));

// Bit-replication constraints (verified R4: absmax == 0):
//  - reductions over K: sequential, ascending k
//  - einsum AXPY: each mul and each add rounded separately, NO fma
//    (fp contract(off)); packed v_pk_mul/v_pk_add round per element ->
//    still bit-exact
//  - correctly-rounded fp32 div/sqrt; eps added in fp32
//  - argmax: strict >, first (lowest d) wins. Split-d partials merge with
//    (score higher) || (score equal && d lower) -- equivalent because every
//    bin's score is computed by exactly one thread with identical op order.

__global__ __launch_bounds__(256) void normalize_cmat_np32(
    const float* __restrict__ cmat, float* __restrict__ bnT) {
#pragma clang fp contract(off)
    const int d = blockIdx.x * 256 + threadIdx.x;   // grid = 4 * 256
    if (d >= D_BINS) return;

    float v[K_DIM];
#pragma unroll
    for (int k = 0; k < K_DIM; ++k) v[k] = cmat[k * D_BINS + d];

    float s = v[0];
#pragma unroll
    for (int k = 1; k < K_DIM; ++k) s = s + v[k];
    const float mean = s / 16.0f;

    float xc[K_DIM], sq[K_DIM];
#pragma unroll
    for (int k = 0; k < K_DIM; ++k) { xc[k] = v[k] - mean; sq[k] = xc[k] * xc[k]; }

    float ss = sq[0];
#pragma unroll
    for (int k = 1; k < K_DIM; ++k) ss = ss + sq[k];
    const float denom = sqrtf(ss) + 1e-10f;

#pragma unroll
    for (int k = 0; k < K_DIM; ++k) bnT[d * K_DIM + k] = xc[k] / denom;
}

// 4 threads per point, 256 bins each, 2 bins per iteration (packed fp32).
__global__ __launch_bounds__(256) void ncc_argmax_split4(
    const float* __restrict__ x, const float* __restrict__ bnT,
    int* __restrict__ out) {
#pragma clang fp contract(off)
    const int t = blockIdx.x * 256 + threadIdx.x;   // grid = 2048 * 256
    const int n = t >> 2;                           // point index
    const int c = t & 3;                            // d-chunk index

    float v[K_DIM];
#pragma unroll
    for (int k = 0; k < K_DIM; ++k) v[k] = x[(size_t)k * N_PTS + n];

    float s = v[0];
#pragma unroll
    for (int k = 1; k < K_DIM; ++k) s = s + v[k];
    const float mean = s / 16.0f;

    float a[K_DIM], sq[K_DIM];
#pragma unroll
    for (int k = 0; k < K_DIM; ++k) { a[k] = v[k] - mean; sq[k] = a[k] * a[k]; }

    float ss = sq[0];
#pragma unroll
    for (int k = 1; k < K_DIM; ++k) ss = ss + sq[k];
    const float denom = sqrtf(ss) + 1e-10f;
#pragma unroll
    for (int k = 0; k < K_DIM; ++k) a[k] = a[k] / denom;

    float best = -3.402823466e38f;
    int   idx  = 0;

    const int d_lo = c * 256;
    const float4* b4 = (const float4*)bnT;

    for (int d = d_lo; d < d_lo + 256; d += 2) {
        const float4 r0 = b4[d * 4 + 0];
        const float4 r1 = b4[d * 4 + 1];
        const float4 r2 = b4[d * 4 + 2];
        const float4 r3 = b4[d * 4 + 3];
        const float4 s0 = b4[d * 4 + 4];
        const float4 s1 = b4[d * 4 + 5];
        const float4 s2 = b4[d * 4 + 6];
        const float4 s3 = b4[d * 4 + 7];

        // packed pair {score(d), score(d+1)}: ascending k, mul then add,
        // each element rounded separately (v_pk_mul_f32 / v_pk_add_f32).
        v2f sc;
        sc = a[0] * (v2f){r0.x, s0.x};
        sc = sc + a[1]  * (v2f){r0.y, s0.y};
        sc = sc + a[2]  * (v2f){r0.z, s0.z};
        sc = sc + a[3]  * (v2f){r0.w, s0.w};
        sc = sc + a[4]  * (v2f){r1.x, s1.x};
        sc = sc + a[5]  * (v2f){r1.y, s1.y};
        sc = sc + a[6]  * (v2f){r1.z, s1.z};
        sc = sc + a[7]  * (v2f){r1.w, s1.w};
        sc = sc + a[8]  * (v2f){r2.x, s2.x};
        sc = sc + a[9]  * (v2f){r2.y, s2.y};
        sc = sc + a[10] * (v2f){r2.z, s2.z};
        sc = sc + a[11] * (v2f){r2.w, s2.w};
        sc = sc + a[12] * (v2f){r3.x, s3.x};
        sc = sc + a[13] * (v2f){r3.y, s3.y};
        sc = sc + a[14] * (v2f){r3.z, s3.z};
        sc = sc + a[15] * (v2f){r3.w, s3.w};

        if (sc.x > best) { best = sc.x; idx = d; }       // lower d first
        if (sc.y > best) { best = sc.y; idx = d + 1; }
    }

    // merge the 4 chunk-partials within each 4-lane group (butterfly).
#pragma unroll
    for (int m = 1; m <= 2; m <<= 1) {
        const float obest = __shfl_xor(best, m, 4);
        const int   oidx  = __shfl_xor(idx,  m, 4);
        if (obest > best || (obest == best && oidx < idx)) {
            best = obest; idx = oidx;
        }
    }

    if (c == 0) out[n] = idx;
}

extern "C" void kernel_launch(void* const* d_in, const int* in_sizes, int n_in,
                              void* d_out, int out_size, void* d_ws, size_t ws_size,
                              hipStream_t stream) {
    const float* x    = (const float*)d_in[0];   // [1, 16, 131072] fp32
    const float* cmat = (const float*)d_in[1];   // [16, 1024] fp32
    int* out = (int*)d_out;                      // [1, 131072] int32
    float* bnT = (float*)d_ws;                   // 1024*16 floats = 64 KB

    normalize_cmat_np32<<<4, 256, 0, stream>>>(cmat, bnT);
    ncc_argmax_split4<<<2048, 256, 0, stream>>>(x, bnT, out);
}

// Round 6
// 175.832 us; speedup vs baseline: 5.3748x; 5.3748x over previous
//
#include <hip/hip_runtime.h>
#include <math.h>

#define N_PTS  131072
#define K_DIM  16
#define D_BINS 1024
#define MARGIN 2e-5f   // |s_fma - s_np| <= ~4.2e-6; 5x safety

// ws layout: [0,4) wl_count | [256,+64KB) bnT | [65792,+512KB) worklist
#define WS_OFF_BN  256
#define WS_OFF_WL  65792

// Exact np normalization of cmat (sequential ascending k, no fma) + zero counter.
__global__ __launch_bounds__(256) void normalize_cmat_np32(
    const float* __restrict__ cmat, float* __restrict__ bnT,
    int* __restrict__ wl_count) {
#pragma clang fp contract(off)
    if (blockIdx.x == 0 && threadIdx.x == 0) *wl_count = 0;
    const int d = blockIdx.x * 256 + threadIdx.x;   // grid = 4 * 256
    if (d >= D_BINS) return;

    float v[K_DIM];
#pragma unroll
    for (int k = 0; k < K_DIM; ++k) v[k] = cmat[k * D_BINS + d];
    float s = v[0];
#pragma unroll
    for (int k = 1; k < K_DIM; ++k) s = s + v[k];
    const float mean = s / 16.0f;
    float xc[K_DIM], sq[K_DIM];
#pragma unroll
    for (int k = 0; k < K_DIM; ++k) { xc[k] = v[k] - mean; sq[k] = xc[k] * xc[k]; }
    float ss = sq[0];
#pragma unroll
    for (int k = 1; k < K_DIM; ++k) ss = ss + sq[k];
    const float denom = sqrtf(ss) + 1e-10f;
#pragma unroll
    for (int k = 0; k < K_DIM; ++k) bnT[d * K_DIM + k] = xc[k] / denom;
}

// Phase 1: 4 waves/block share 64 points; wave w scans d in [256w, 256w+256)
// (d wave-uniform -> scalar b loads). fmaf screening scores, top-2 tracking,
// LDS merge, margin test; ambiguous points -> worklist.
__global__ __launch_bounds__(256) void ncc_phase1(
    const float* __restrict__ x, const float* __restrict__ bnT,
    int* __restrict__ out, int* __restrict__ wl, int* __restrict__ wl_count) {
#pragma clang fp contract(off)
    const int lane = threadIdx.x & 63;
    const int wv   = threadIdx.x >> 6;
    const int n    = blockIdx.x * 64 + lane;        // grid = 2048 * 256

    // exact np normalization of a (contract off; explicit fmaf below is
    // unaffected by the pragma)
    float a[K_DIM];
    {
        float v[K_DIM];
#pragma unroll
        for (int k = 0; k < K_DIM; ++k) v[k] = x[(size_t)k * N_PTS + n];
        float s = v[0];
#pragma unroll
        for (int k = 1; k < K_DIM; ++k) s = s + v[k];
        const float mean = s / 16.0f;
        float sq[K_DIM];
#pragma unroll
        for (int k = 0; k < K_DIM; ++k) { a[k] = v[k] - mean; sq[k] = a[k] * a[k]; }
        float ss = sq[0];
#pragma unroll
        for (int k = 1; k < K_DIM; ++k) ss = ss + sq[k];
        const float denom = sqrtf(ss) + 1e-10f;
#pragma unroll
        for (int k = 0; k < K_DIM; ++k) a[k] = a[k] / denom;
    }

    const int d0 = __builtin_amdgcn_readfirstlane(wv) << 8;  // force uniform

    float b1 = -3.402823466e38f, b2 = -3.402823466e38f;
    int   i1 = 0;

    for (int j = 0; j < 256; j += 2) {
        const float4* r = (const float4*)(bnT + (size_t)(d0 + j) * K_DIM);
        const float4 r0 = r[0], r1 = r[1], r2 = r[2], r3 = r[3];
        const float4 s0 = r[4], s1 = r[5], s2 = r[6], s3 = r[7];

        float u = a[0] * r0.x;
        u = fmaf(a[1],  r0.y, u); u = fmaf(a[2],  r0.z, u); u = fmaf(a[3],  r0.w, u);
        u = fmaf(a[4],  r1.x, u); u = fmaf(a[5],  r1.y, u); u = fmaf(a[6],  r1.z, u);
        u = fmaf(a[7],  r1.w, u); u = fmaf(a[8],  r2.x, u); u = fmaf(a[9],  r2.y, u);
        u = fmaf(a[10], r2.z, u); u = fmaf(a[11], r2.w, u); u = fmaf(a[12], r3.x, u);
        u = fmaf(a[13], r3.y, u); u = fmaf(a[14], r3.z, u); u = fmaf(a[15], r3.w, u);

        float w = a[0] * s0.x;
        w = fmaf(a[1],  s0.y, w); w = fmaf(a[2],  s0.z, w); w = fmaf(a[3],  s0.w, w);
        w = fmaf(a[4],  s1.x, w); w = fmaf(a[5],  s1.y, w); w = fmaf(a[6],  s1.z, w);
        w = fmaf(a[7],  s1.w, w); w = fmaf(a[8],  s2.x, w); w = fmaf(a[9],  s2.y, w);
        w = fmaf(a[10], s2.z, w); w = fmaf(a[11], s2.w, w); w = fmaf(a[12], s3.x, w);
        w = fmaf(a[13], s3.y, w); w = fmaf(a[14], s3.z, w); w = fmaf(a[15], s3.w, w);

        if (u > b1) { b2 = b1; b1 = u; i1 = d0 + j; }     else b2 = fmaxf(b2, u);
        if (w > b1) { b2 = b1; b1 = w; i1 = d0 + j + 1; } else b2 = fmaxf(b2, w);
    }

    __shared__ float sb1[4][64];
    __shared__ float sb2[4][64];
    __shared__ int   si1[4][64];
    sb1[wv][lane] = b1; sb2[wv][lane] = b2; si1[wv][lane] = i1;
    __syncthreads();

    if (wv == 0) {
        float g1 = sb1[0][lane]; int gi = si1[0][lane]; int cs = 0;
#pragma unroll
        for (int c = 1; c < 4; ++c)
            if (sb1[c][lane] > g1) { g1 = sb1[c][lane]; gi = si1[c][lane]; cs = c; }
        float g2 = sb2[cs][lane];
#pragma unroll
        for (int c = 0; c < 4; ++c)
            if (c != cs) g2 = fmaxf(g2, sb1[c][lane]);

        if (g1 - g2 > MARGIN) {
            out[n] = gi;
        } else {
            const int p = atomicAdd(wl_count, 1);
            wl[p] = n;
        }
    }
}

// Phase 2: exact np-order rescan of worklisted points. 16 lanes per point
// (64 bins each, split-d is bit-safe: each bin's score computed by one lane
// with the exact np op sequence); merge prefers higher score, then lower d.
__global__ __launch_bounds__(256) void ncc_exact_refine(
    const float* __restrict__ x, const float* __restrict__ bnT,
    int* __restrict__ out, const int* __restrict__ wl,
    const int* __restrict__ wl_count) {
#pragma clang fp contract(off)
    const int count  = *wl_count;
    const int need   = count * 16;
    const int stride = gridDim.x * 256;
    for (int t = blockIdx.x * 256 + threadIdx.x; t < need; t += stride) {
        const int n = wl[t >> 4];
        const int c = t & 15;

        float a[K_DIM];
        {
            float v[K_DIM];
#pragma unroll
            for (int k = 0; k < K_DIM; ++k) v[k] = x[(size_t)k * N_PTS + n];
            float s = v[0];
#pragma unroll
            for (int k = 1; k < K_DIM; ++k) s = s + v[k];
            const float mean = s / 16.0f;
            float sq[K_DIM];
#pragma unroll
            for (int k = 0; k < K_DIM; ++k) { a[k] = v[k] - mean; sq[k] = a[k] * a[k]; }
            float ss = sq[0];
#pragma unroll
            for (int k = 1; k < K_DIM; ++k) ss = ss + sq[k];
            const float denom = sqrtf(ss) + 1e-10f;
#pragma unroll
            for (int k = 0; k < K_DIM; ++k) a[k] = a[k] / denom;
        }

        float best = -3.402823466e38f;
        int   idx  = 0;
        const float4* b4 = (const float4*)bnT;
        const int d_lo = c * 64;
        for (int d = d_lo; d < d_lo + 64; ++d) {
            const float4 q0 = b4[d * 4 + 0];
            const float4 q1 = b4[d * 4 + 1];
            const float4 q2 = b4[d * 4 + 2];
            const float4 q3 = b4[d * 4 + 3];
            float sc;
            sc = a[0] * q0.x;
            sc = sc + a[1]  * q0.y; sc = sc + a[2]  * q0.z; sc = sc + a[3]  * q0.w;
            sc = sc + a[4]  * q1.x; sc = sc + a[5]  * q1.y; sc = sc + a[6]  * q1.z;
            sc = sc + a[7]  * q1.w; sc = sc + a[8]  * q2.x; sc = sc + a[9]  * q2.y;
            sc = sc + a[10] * q2.z; sc = sc + a[11] * q2.w; sc = sc + a[12] * q3.x;
            sc = sc + a[13] * q3.y; sc = sc + a[14] * q3.z; sc = sc + a[15] * q3.w;
            if (sc > best) { best = sc; idx = d; }
        }

#pragma unroll
        for (int m = 1; m <= 8; m <<= 1) {
            const float ob = __shfl_xor(best, m, 16);
            const int   oi = __shfl_xor(idx,  m, 16);
            if (ob > best || (ob == best && oi < idx)) { best = ob; idx = oi; }
        }
        if (c == 0) out[n] = idx;
    }
}

extern "C" void kernel_launch(void* const* d_in, const int* in_sizes, int n_in,
                              void* d_out, int out_size, void* d_ws, size_t ws_size,
                              hipStream_t stream) {
    const float* x    = (const float*)d_in[0];   // [1, 16, 131072] fp32
    const float* cmat = (const float*)d_in[1];   // [16, 1024] fp32
    int* out = (int*)d_out;                      // [1, 131072] int32
    char* ws = (char*)d_ws;

    int*   wl_count = (int*)ws;
    float* bnT      = (float*)(ws + WS_OFF_BN);
    int*   wl       = (int*)(ws + WS_OFF_WL);

    normalize_cmat_np32<<<4, 256, 0, stream>>>(cmat, bnT, wl_count);
    ncc_phase1<<<2048, 256, 0, stream>>>(x, bnT, out, wl, wl_count);
    ncc_exact_refine<<<128, 256, 0, stream>>>(x, bnT, out, wl, wl_count);
}

// Round 7
// 134.703 us; speedup vs baseline: 7.0159x; 1.3053x over previous
//
#include <hip/hip_runtime.h>
#include <math.h>

#define N_PTS  131072
#define K_DIM  16
#define D_BINS 1024
#define MARGIN 2e-5f   // screen-vs-np deviation bound ~3e-6; 7x safety

typedef float v2f __attribute__((ext_vector_type(2)));

// ws layout (hybrid):
// [0,4) wl_count | [256,+64K) bnTi (pair-interleaved) | [65792,+64K) bnT (rows)
// | [131328,+512K) worklist
#define WS_OFF_BNI 256
#define WS_OFF_BN  65792
#define WS_OFF_WL  131328
#define WS_NEED    655616

// np-exact cmat normalization; writes row layout (refine) + pair-interleaved
// (phase1 packed screen); zeroes worklist counter.
__global__ __launch_bounds__(256) void normalize_both(
    const float* __restrict__ cmat, float* __restrict__ bnT,
    float* __restrict__ bnTi, int* __restrict__ wl_count) {
#pragma clang fp contract(off)
    if (blockIdx.x == 0 && threadIdx.x == 0) *wl_count = 0;
    const int d = blockIdx.x * 256 + threadIdx.x;   // grid = 4 * 256
    if (d >= D_BINS) return;

    float v[K_DIM];
#pragma unroll
    for (int k = 0; k < K_DIM; ++k) v[k] = cmat[k * D_BINS + d];
    float s = v[0];
#pragma unroll
    for (int k = 1; k < K_DIM; ++k) s = s + v[k];
    const float mean = s / 16.0f;
    float xc[K_DIM], sq[K_DIM];
#pragma unroll
    for (int k = 0; k < K_DIM; ++k) { xc[k] = v[k] - mean; sq[k] = xc[k] * xc[k]; }
    float ss = sq[0];
#pragma unroll
    for (int k = 1; k < K_DIM; ++k) ss = ss + sq[k];
    const float denom = sqrtf(ss) + 1e-10f;

    const int p = d >> 1, r = d & 1;
#pragma unroll
    for (int k = 0; k < K_DIM; ++k) {
        const float t = xc[k] / denom;
        bnT[d * K_DIM + k] = t;
        bnTi[p * 32 + 2 * k + r] = t;
    }
}

// Phase 1: 8 waves/block share 64 points; wave w scans d in [128w,128w+128)
// (wave-uniform). Packed-fp32 screen (v_pk_fma), top-2 + LDS merge, margin
// test; ambiguous points -> worklist.
__global__ __launch_bounds__(512) void ncc_phase1(
    const float* __restrict__ x, const float* __restrict__ bnTi,
    int* __restrict__ out, int* __restrict__ wl, int* __restrict__ wl_count) {
#pragma clang fp contract(off)
    const int lane = threadIdx.x & 63;
    const int wv   = threadIdx.x >> 6;              // 0..7
    const int n    = blockIdx.x * 64 + lane;        // grid = 2048 * 512

    // np-exact normalization of a (sequential ascending k, no fma)
    float a[K_DIM];
    {
        float v[K_DIM];
#pragma unroll
        for (int k = 0; k < K_DIM; ++k) v[k] = x[(size_t)k * N_PTS + n];
        float s = v[0];
#pragma unroll
        for (int k = 1; k < K_DIM; ++k) s = s + v[k];
        const float mean = s / 16.0f;
        float sq[K_DIM];
#pragma unroll
        for (int k = 0; k < K_DIM; ++k) { a[k] = v[k] - mean; sq[k] = a[k] * a[k]; }
        float ss = sq[0];
#pragma unroll
        for (int k = 1; k < K_DIM; ++k) ss = ss + sq[k];
        const float denom = sqrtf(ss) + 1e-10f;
#pragma unroll
        for (int k = 0; k < K_DIM; ++k) a[k] = a[k] / denom;
    }

    v2f a2[K_DIM];
#pragma unroll
    for (int k = 0; k < K_DIM; ++k) a2[k] = (v2f){a[k], a[k]};

    const int d0 = __builtin_amdgcn_readfirstlane(wv) << 7;

    float b1 = -3.402823466e38f, b2 = -3.402823466e38f;
    int   i1 = 0;

    {
#pragma clang fp contract(fast)
        for (int j = 0; j < 128; j += 2) {
            const v2f* bp = (const v2f*)(bnTi + (size_t)(d0 + j) * K_DIM);
            v2f e = a2[0] * bp[0];
            e = e + a2[1] * bp[1];  e = e + a2[2] * bp[2];
            e = e + a2[3] * bp[3];  e = e + a2[4] * bp[4];
            e = e + a2[5] * bp[5];  e = e + a2[6] * bp[6];
            e = e + a2[7] * bp[7];
            v2f f = a2[8] * bp[8];
            f = f + a2[9]  * bp[9];  f = f + a2[10] * bp[10];
            f = f + a2[11] * bp[11]; f = f + a2[12] * bp[12];
            f = f + a2[13] * bp[13]; f = f + a2[14] * bp[14];
            f = f + a2[15] * bp[15];
            const v2f sc = e + f;

            const float u = sc.x, w = sc.y;
            if (u > b1) { b2 = b1; b1 = u; i1 = d0 + j; }     else b2 = fmaxf(b2, u);
            if (w > b1) { b2 = b1; b1 = w; i1 = d0 + j + 1; } else b2 = fmaxf(b2, w);
        }
    }

    __shared__ float sb1[8][64];
    __shared__ float sb2[8][64];
    __shared__ int   si1[8][64];
    sb1[wv][lane] = b1; sb2[wv][lane] = b2; si1[wv][lane] = i1;
    __syncthreads();

    if (wv == 0) {
        float g1 = sb1[0][lane]; int gi = si1[0][lane]; int cs = 0;
#pragma unroll
        for (int c = 1; c < 8; ++c)
            if (sb1[c][lane] > g1) { g1 = sb1[c][lane]; gi = si1[c][lane]; cs = c; }
        float g2 = sb2[cs][lane];
#pragma unroll
        for (int c = 0; c < 8; ++c)
            if (c != cs) g2 = fmaxf(g2, sb1[c][lane]);

        if (g1 - g2 > MARGIN) {
            out[n] = gi;
        } else {
            const int p = atomicAdd(wl_count, 1);
            wl[p] = n;
        }
    }
}

// Phase 2: np-exact rescan, ONE WAVE PER POINT. Lane L owns bins d = t*64+L
// (each bin scored once, exact np op order); butterfly merge prefers higher
// score then lower d == global first-max-wins.
__global__ __launch_bounds__(256) void ncc_exact_refine(
    const float* __restrict__ x, const float* __restrict__ bnT,
    int* __restrict__ out, const int* __restrict__ wl,
    const int* __restrict__ wl_count) {
#pragma clang fp contract(off)
    const int count  = *wl_count;
    const int lane   = threadIdx.x & 63;
    const int wave   = (blockIdx.x * 256 + threadIdx.x) >> 6;
    const int nwaves = (gridDim.x * 256) >> 6;

    for (int i = wave; i < count; i += nwaves) {
        const int n = wl[i];

        float a[K_DIM];
        {
            float v[K_DIM];
#pragma unroll
            for (int k = 0; k < K_DIM; ++k) v[k] = x[(size_t)k * N_PTS + n];
            float s = v[0];
#pragma unroll
            for (int k = 1; k < K_DIM; ++k) s = s + v[k];
            const float mean = s / 16.0f;
            float sq[K_DIM];
#pragma unroll
            for (int k = 0; k < K_DIM; ++k) { a[k] = v[k] - mean; sq[k] = a[k] * a[k]; }
            float ss = sq[0];
#pragma unroll
            for (int k = 1; k < K_DIM; ++k) ss = ss + sq[k];
            const float denom = sqrtf(ss) + 1e-10f;
#pragma unroll
            for (int k = 0; k < K_DIM; ++k) a[k] = a[k] / denom;
        }

        float best = -3.402823466e38f;
        int   idx  = 0x7fffffff;
        for (int t = 0; t < 16; ++t) {
            const int d = t * 64 + lane;
            const float4* q = (const float4*)(bnT + (size_t)d * K_DIM);
            const float4 q0 = q[0], q1 = q[1], q2 = q[2], q3 = q[3];
            float sc;
            sc = a[0] * q0.x;
            sc = sc + a[1]  * q0.y; sc = sc + a[2]  * q0.z; sc = sc + a[3]  * q0.w;
            sc = sc + a[4]  * q1.x; sc = sc + a[5]  * q1.y; sc = sc + a[6]  * q1.z;
            sc = sc + a[7]  * q1.w; sc = sc + a[8]  * q2.x; sc = sc + a[9]  * q2.y;
            sc = sc + a[10] * q2.z; sc = sc + a[11] * q2.w; sc = sc + a[12] * q3.x;
            sc = sc + a[13] * q3.y; sc = sc + a[14] * q3.z; sc = sc + a[15] * q3.w;
            if (sc > best) { best = sc; idx = d; }
        }

#pragma unroll
        for (int m = 1; m <= 32; m <<= 1) {
            const float ob = __shfl_xor(best, m);
            const int   oi = __shfl_xor(idx,  m);
            if (ob > best || (ob == best && oi < idx)) { best = ob; idx = oi; }
        }
        if (lane == 0) out[n] = idx;
    }
}

// Fallback (small ws): proven-exact single-kernel scan (R4).
__global__ __launch_bounds__(256) void ncc_argmax_np32(
    const float* __restrict__ x, const float* __restrict__ bnT,
    int* __restrict__ out) {
#pragma clang fp contract(off)
    const int n = blockIdx.x * 256 + threadIdx.x;

    float v[K_DIM];
#pragma unroll
    for (int k = 0; k < K_DIM; ++k) v[k] = x[(size_t)k * N_PTS + n];
    float s = v[0];
#pragma unroll
    for (int k = 1; k < K_DIM; ++k) s = s + v[k];
    const float mean = s / 16.0f;
    float a[K_DIM], sq[K_DIM];
#pragma unroll
    for (int k = 0; k < K_DIM; ++k) { a[k] = v[k] - mean; sq[k] = a[k] * a[k]; }
    float ss = sq[0];
#pragma unroll
    for (int k = 1; k < K_DIM; ++k) ss = ss + sq[k];
    const float denom = sqrtf(ss) + 1e-10f;
#pragma unroll
    for (int k = 0; k < K_DIM; ++k) a[k] = a[k] / denom;

    float best = -3.402823466e38f;
    int   idx  = 0;
    const float4* b4 = (const float4*)bnT;
#pragma unroll 2
    for (int d = 0; d < D_BINS; ++d) {
        const float4 q0 = b4[d * 4 + 0];
        const float4 q1 = b4[d * 4 + 1];
        const float4 q2 = b4[d * 4 + 2];
        const float4 q3 = b4[d * 4 + 3];
        float sc;
        sc = a[0] * q0.x;
        sc = sc + a[1]  * q0.y; sc = sc + a[2]  * q0.z; sc = sc + a[3]  * q0.w;
        sc = sc + a[4]  * q1.x; sc = sc + a[5]  * q1.y; sc = sc + a[6]  * q1.z;
        sc = sc + a[7]  * q1.w; sc = sc + a[8]  * q2.x; sc = sc + a[9]  * q2.y;
        sc = sc + a[10] * q2.z; sc = sc + a[11] * q2.w; sc = sc + a[12] * q3.x;
        sc = sc + a[13] * q3.y; sc = sc + a[14] * q3.z; sc = sc + a[15] * q3.w;
        if (sc > best) { best = sc; idx = d; }
    }
    out[n] = idx;
}

extern "C" void kernel_launch(void* const* d_in, const int* in_sizes, int n_in,
                              void* d_out, int out_size, void* d_ws, size_t ws_size,
                              hipStream_t stream) {
    const float* x    = (const float*)d_in[0];   // [1, 16, 131072] fp32
    const float* cmat = (const float*)d_in[1];   // [16, 1024] fp32
    int* out = (int*)d_out;                      // [1, 131072] int32
    char* ws = (char*)d_ws;

    if (ws_size >= WS_NEED) {
        int*   wl_count = (int*)ws;
        float* bnTi     = (float*)(ws + WS_OFF_BNI);
        float* bnT      = (float*)(ws + WS_OFF_BN);
        int*   wl       = (int*)(ws + WS_OFF_WL);

        normalize_both<<<4, 256, 0, stream>>>(cmat, bnT, bnTi, wl_count);
        ncc_phase1<<<2048, 512, 0, stream>>>(x, bnTi, out, wl, wl_count);
        ncc_exact_refine<<<512, 256, 0, stream>>>(x, bnT, out, wl, wl_count);
    } else {
        float* bnT = (float*)(ws + 256);
        normalize_both<<<4, 256, 0, stream>>>(cmat, bnT, bnT, nullptr); // row copy unused twice is safe? no:
        // safer: dedicated row-only normalize via same kernel writing both into
        // the same 64K region is NOT safe; use exact kernel with row layout:
        // (re-run normalize_both with bnTi pointing at a scratch 64K after bnT)
        // ws guaranteed >= 131328 here? If not, last resort: reuse bnT for both
        // is incorrect; assume >= 128K+256 which R1 demonstrated.
        float* bnTi_scratch = (float*)(ws + 256 + 65536);
        normalize_both<<<4, 256, 0, stream>>>(cmat, bnT, bnTi_scratch, nullptr);
        ncc_argmax_np32<<<512, 256, 0, stream>>>(x, bnT, out);
    }
}

// Round 8
// 118.741 us; speedup vs baseline: 7.9590x; 1.1344x over previous
//
#include <hip/hip_runtime.h>
#include <hip/hip_bf16.h>
#include <math.h>

#define N_PTS  131072
#define K_DIM  16
#define D_BINS 1024
#define MARGIN 1e-4f   // |screen - np32| bound ~1.5e-5; ~7x safety

typedef short bf16x8 __attribute__((ext_vector_type(8)));
typedef float f32x4  __attribute__((ext_vector_type(4)));

// ws layout (bytes):
// [0,4) wl_count | [64,+64K) bnT rows | [65600,+32K) B1 hi-frags (lanes 0-31)
// | [98368,+32K) B2 lo-frags | [131136,+16) zero block | [131152,+512K) wl
#define WS_OFF_BN    64
#define WS_OFF_B1    (WS_OFF_BN + 65536)
#define WS_OFF_B2    (WS_OFF_B1 + 32768)
#define WS_OFF_ZERO  (WS_OFF_B2 + 32768)
#define WS_OFF_WL    (WS_OFF_ZERO + 16)
#define WS_NEED      (WS_OFF_WL + 4 * N_PTS)   // 655,440 <= proven ws floor

// np-exact normalization over K (sequential ascending k, no fma).
__device__ __forceinline__ void norm_np(const float* __restrict__ p,
                                        int stride, int n, float* __restrict__ a) {
#pragma clang fp contract(off)
    float v[K_DIM];
#pragma unroll
    for (int k = 0; k < K_DIM; ++k) v[k] = p[(size_t)k * stride + n];
    float s = v[0];
#pragma unroll
    for (int k = 1; k < K_DIM; ++k) s = s + v[k];
    const float mean = s / 16.0f;
    float sq[K_DIM];
#pragma unroll
    for (int k = 0; k < K_DIM; ++k) { a[k] = v[k] - mean; sq[k] = a[k] * a[k]; }
    float ss = sq[0];
#pragma unroll
    for (int k = 1; k < K_DIM; ++k) ss = ss + sq[k];
    const float denom = sqrtf(ss) + 1e-10f;
#pragma unroll
    for (int k = 0; k < K_DIM; ++k) a[k] = a[k] / denom;
}

__device__ __forceinline__ unsigned short bf16_bits(float f) {
    __hip_bfloat16 h = __float2bfloat16(f);   // RNE
    unsigned short u;
    __builtin_memcpy(&u, &h, 2);
    return u;
}
__device__ __forceinline__ float bf16_val(float f) {
    return __bfloat162float(__float2bfloat16(f));
}

// Kernel 1: normalize cmat (np-exact), write row layout (refine) + hi/lo
// MFMA B-operand fragments; zero wl counter + zero block.
__global__ __launch_bounds__(256) void prep_b(
    const float* __restrict__ cmat, float* __restrict__ bnT,
    unsigned short* __restrict__ B1, unsigned short* __restrict__ B2,
    unsigned short* __restrict__ zblk, int* __restrict__ wl_count) {
#pragma clang fp contract(off)
    if (blockIdx.x == 0) {
        if (threadIdx.x == 0) *wl_count = 0;
        if (threadIdx.x < 8) zblk[threadIdx.x] = 0;
    }
    const int d = blockIdx.x * 256 + threadIdx.x;   // grid = 4 * 256
    if (d >= D_BINS) return;

    float t[K_DIM];
    norm_np(cmat, D_BINS, d, t);

    const int tile = d >> 4, n = d & 15;
#pragma unroll
    for (int k = 0; k < K_DIM; ++k) {
        bnT[d * K_DIM + k] = t[k];
        const float hi_f = bf16_val(t[k]);
        const int idx = tile * 256 + ((k >> 3) * 16 + n) * 8 + (k & 7);
        B1[idx] = bf16_bits(t[k]);          // hi
        B2[idx] = bf16_bits(t[k] - hi_f);   // lo
    }
}

// Kernel 2: MFMA screen. One wave owns 64 points (4 16-row tiles, A-frags
// resident); iterates 64 bin-tiles with 2 chained MFMAs per tile:
//   score = (a_hi+a_lo)·b_hi + a_hi·b_lo   (K=32 packed hi|lo)
// Per-lane top-2 across its column, 16-lane shfl merge, margin test.
__global__ __launch_bounds__(256) void mfma_screen(
    const float* __restrict__ x, const unsigned short* __restrict__ B1,
    const unsigned short* __restrict__ B2, const unsigned short* __restrict__ zblk,
    int* __restrict__ out, int* __restrict__ wl, int* __restrict__ wl_count) {
#pragma clang fp contract(off)
    const int lane = threadIdx.x & 63;
    const int wv   = threadIdx.x >> 6;
    const int W    = blockIdx.x * 4 + wv;     // grid = 512 * 256 -> 2048 waves
    const int P    = W * 64;
    const int m    = lane & 15;               // col / point-in-tile
    const int q    = lane >> 4;               // quad -> k-chunk

    // Build A fragments: A[m][kp], kp=(lane>>4)*8+j; kp<16 -> hi[kp],
    // kp>=16 -> lo[kp-16]. Quads 0,1 carry hi[q*8+j]; quads 2,3 lo[(q-2)*8+j].
    bf16x8 A[4];
#pragma unroll
    for (int t = 0; t < 4; ++t) {
        float a[K_DIM];
        norm_np(x, N_PTS, P + t * 16 + m, a);
        unsigned short els[8];
#pragma unroll
        for (int j = 0; j < 8; ++j) {
            const int k = (q & 1) * 8 + j;
            if (q < 2) els[j] = bf16_bits(a[k]);
            else       els[j] = bf16_bits(a[k] - bf16_val(a[k]));
        }
        __builtin_memcpy(&A[t], els, 16);
    }

    float b1v[4][4], b2v[4][4];
    int   i1v[4][4];
#pragma unroll
    for (int t = 0; t < 4; ++t)
#pragma unroll
        for (int r = 0; r < 4; ++r) {
            b1v[t][r] = -3.402823466e38f; b2v[t][r] = -3.402823466e38f;
            i1v[t][r] = 0;
        }

    // B1: all 64 lanes mirror lanes 0-31 (hi repeated in both K-halves).
    // B2: lanes 32-63 read the zero block (kills the a_lo half).
    const unsigned short* b1p = B1 + (size_t)(lane & 31) * 8;
    const unsigned short* b2p = (lane < 32) ? (B2 + (size_t)lane * 8) : zblk;
    const int b2s = (lane < 32) ? 256 : 0;

    for (int i = 0; i < 64; ++i) {
        bf16x8 bf1, bf2;
        __builtin_memcpy(&bf1, b1p + (size_t)i * 256, 16);
        __builtin_memcpy(&bf2, b2p + (size_t)i * b2s, 16);

        f32x4 acc[4];
#pragma unroll
        for (int t = 0; t < 4; ++t)
            acc[t] = __builtin_amdgcn_mfma_f32_16x16x32_bf16(
                A[t], bf1, (f32x4){0.f, 0.f, 0.f, 0.f}, 0, 0, 0);
#pragma unroll
        for (int t = 0; t < 4; ++t)
            acc[t] = __builtin_amdgcn_mfma_f32_16x16x32_bf16(
                A[t], bf2, acc[t], 0, 0, 0);

        const int d = i * 16 + m;   // C/D: col = lane&15
#pragma unroll
        for (int t = 0; t < 4; ++t)
#pragma unroll
            for (int r = 0; r < 4; ++r) {
                const float sc = acc[t][r];   // row = q*4 + r
                if (sc > b1v[t][r]) { b2v[t][r] = b1v[t][r]; b1v[t][r] = sc; i1v[t][r] = d; }
                else                 b2v[t][r] = fmaxf(b2v[t][r], sc);
            }
    }

    // Merge top-2 across the 16 cols of each quad-group; prefer higher score,
    // then lower d (== np first-max-wins; exact ties fall to refine anyway).
#pragma unroll
    for (int t = 0; t < 4; ++t)
#pragma unroll
        for (int r = 0; r < 4; ++r) {
            float B1v = b1v[t][r], B2v = b2v[t][r];
            int   I1  = i1v[t][r];
#pragma unroll
            for (int s = 1; s <= 8; s <<= 1) {
                const float ob1 = __shfl_xor(B1v, s, 16);
                const float ob2 = __shfl_xor(B2v, s, 16);
                const int   oi  = __shfl_xor(I1,  s, 16);
                if (ob1 > B1v || (ob1 == B1v && oi < I1)) {
                    B2v = fmaxf(B1v, ob2); B1v = ob1; I1 = oi;
                } else {
                    B2v = fmaxf(B2v, ob1);
                }
            }
            if (m == 0) {
                const int p = P + t * 16 + q * 4 + r;
                if (B1v - B2v > MARGIN) {
                    out[p] = I1;
                } else {
                    const int pos = atomicAdd(wl_count, 1);
                    wl[pos] = p;
                }
            }
        }
}

// Kernel 3: np-exact rescan, one wave per worklisted point (proven R7).
__global__ __launch_bounds__(256) void ncc_exact_refine(
    const float* __restrict__ x, const float* __restrict__ bnT,
    int* __restrict__ out, const int* __restrict__ wl,
    const int* __restrict__ wl_count) {
#pragma clang fp contract(off)
    const int count  = *wl_count;
    const int lane   = threadIdx.x & 63;
    const int wave   = (blockIdx.x * 256 + threadIdx.x) >> 6;
    const int nwaves = (gridDim.x * 256) >> 6;

    for (int i = wave; i < count; i += nwaves) {
        const int n = wl[i];
        float a[K_DIM];
        norm_np(x, N_PTS, n, a);

        float best = -3.402823466e38f;
        int   idx  = 0x7fffffff;
        const float4* b4 = (const float4*)bnT;
        for (int t = 0; t < 16; ++t) {
            const int d = t * 64 + lane;
            const float4 q0 = b4[d * 4 + 0];
            const float4 q1 = b4[d * 4 + 1];
            const float4 q2 = b4[d * 4 + 2];
            const float4 q3 = b4[d * 4 + 3];
            float sc;
            sc = a[0] * q0.x;
            sc = sc + a[1]  * q0.y; sc = sc + a[2]  * q0.z; sc = sc + a[3]  * q0.w;
            sc = sc + a[4]  * q1.x; sc = sc + a[5]  * q1.y; sc = sc + a[6]  * q1.z;
            sc = sc + a[7]  * q1.w; sc = sc + a[8]  * q2.x; sc = sc + a[9]  * q2.y;
            sc = sc + a[10] * q2.z; sc = sc + a[11] * q2.w; sc = sc + a[12] * q3.x;
            sc = sc + a[13] * q3.y; sc = sc + a[14] * q3.z; sc = sc + a[15] * q3.w;
            if (sc > best) { best = sc; idx = d; }
        }
#pragma unroll
        for (int mk = 1; mk <= 32; mk <<= 1) {
            const float ob = __shfl_xor(best, mk);
            const int   oi = __shfl_xor(idx,  mk);
            if (ob > best || (ob == best && oi < idx)) { best = ob; idx = oi; }
        }
        if (lane == 0) out[n] = idx;
    }
}

// Fallback (small ws): proven-exact full scan (R4, 194 us).
__global__ __launch_bounds__(256) void ncc_argmax_np32(
    const float* __restrict__ x, const float* __restrict__ bnT,
    int* __restrict__ out) {
#pragma clang fp contract(off)
    const int n = blockIdx.x * 256 + threadIdx.x;
    float a[K_DIM];
    norm_np(x, N_PTS, n, a);

    float best = -3.402823466e38f;
    int   idx  = 0;
    const float4* b4 = (const float4*)bnT;
#pragma unroll 2
    for (int d = 0; d < D_BINS; ++d) {
        const float4 q0 = b4[d * 4 + 0];
        const float4 q1 = b4[d * 4 + 1];
        const float4 q2 = b4[d * 4 + 2];
        const float4 q3 = b4[d * 4 + 3];
        float sc;
        sc = a[0] * q0.x;
        sc = sc + a[1]  * q0.y; sc = sc + a[2]  * q0.z; sc = sc + a[3]  * q0.w;
        sc = sc + a[4]  * q1.x; sc = sc + a[5]  * q1.y; sc = sc + a[6]  * q1.z;
        sc = sc + a[7]  * q1.w; sc = sc + a[8]  * q2.x; sc = sc + a[9]  * q2.y;
        sc = sc + a[10] * q2.z; sc = sc + a[11] * q2.w; sc = sc + a[12] * q3.x;
        sc = sc + a[13] * q3.y; sc = sc + a[14] * q3.z; sc = sc + a[15] * q3.w;
        if (sc > best) { best = sc; idx = d; }
    }
    out[n] = idx;
}

__global__ __launch_bounds__(256) void normalize_rows_only(
    const float* __restrict__ cmat, float* __restrict__ bnT) {
#pragma clang fp contract(off)
    const int d = blockIdx.x * 256 + threadIdx.x;
    if (d >= D_BINS) return;
    float t[K_DIM];
    norm_np(cmat, D_BINS, d, t);
#pragma unroll
    for (int k = 0; k < K_DIM; ++k) bnT[d * K_DIM + k] = t[k];
}

extern "C" void kernel_launch(void* const* d_in, const int* in_sizes, int n_in,
                              void* d_out, int out_size, void* d_ws, size_t ws_size,
                              hipStream_t stream) {
    const float* x    = (const float*)d_in[0];   // [1, 16, 131072] fp32
    const float* cmat = (const float*)d_in[1];   // [16, 1024] fp32
    int* out = (int*)d_out;                      // [1, 131072] int32
    char* ws = (char*)d_ws;

    if (ws_size >= (size_t)WS_NEED) {
        int*            wl_count = (int*)ws;
        float*          bnT      = (float*)(ws + WS_OFF_BN);
        unsigned short* B1       = (unsigned short*)(ws + WS_OFF_B1);
        unsigned short* B2       = (unsigned short*)(ws + WS_OFF_B2);
        unsigned short* zblk     = (unsigned short*)(ws + WS_OFF_ZERO);
        int*            wl       = (int*)(ws + WS_OFF_WL);

        prep_b<<<4, 256, 0, stream>>>(cmat, bnT, B1, B2, zblk, wl_count);
        mfma_screen<<<512, 256, 0, stream>>>(x, B1, B2, zblk, out, wl, wl_count);
        ncc_exact_refine<<<256, 256, 0, stream>>>(x, bnT, out, wl, wl_count);
    } else {
        float* bnT = (float*)(ws + WS_OFF_BN);
        normalize_rows_only<<<4, 256, 0, stream>>>(cmat, bnT);
        ncc_argmax_np32<<<512, 256, 0, stream>>>(x, bnT, out);
    }
}

// Round 9
// 108.765 us; speedup vs baseline: 8.6891x; 1.0917x over previous
//
#include <hip/hip_runtime.h>
#include <hip/hip_bf16.h>
#include <math.h>

#define N_PTS  131072
#define K_DIM  16
#define D_BINS 1024
// packed-screen commit margin: covers quantize (2^-11=4.88e-4) + screen err
// (~5e-5) with room: commit => true np gap > 6e-4-4.88e-4-5e-5 ~ 6e-5 > 0
#define MARGIN_P 6e-4f

typedef short bf16x8 __attribute__((ext_vector_type(8)));
typedef float f32x4  __attribute__((ext_vector_type(4)));

// ws layout (bytes):
// [0,4) wl_count | [64,+64K) bnT rows | [65600,+64K) Bpack = B1(32K)|B2(32K)
// | [131136,+512K) worklist      total 655,424 <= proven ws floor (R6: 655,616)
#define WS_OFF_BN  64
#define WS_OFF_B   65600
#define WS_OFF_WL  131136
#define WS_NEED    655424

// np-exact normalization over K (sequential ascending k, no fma).
__device__ __forceinline__ void norm_np(const float* __restrict__ p,
                                        int stride, int n, float* __restrict__ a) {
#pragma clang fp contract(off)
    float v[K_DIM];
#pragma unroll
    for (int k = 0; k < K_DIM; ++k) v[k] = p[(size_t)k * stride + n];
    float s = v[0];
#pragma unroll
    for (int k = 1; k < K_DIM; ++k) s = s + v[k];
    const float mean = s / 16.0f;
    float sq[K_DIM];
#pragma unroll
    for (int k = 0; k < K_DIM; ++k) { a[k] = v[k] - mean; sq[k] = a[k] * a[k]; }
    float ss = sq[0];
#pragma unroll
    for (int k = 1; k < K_DIM; ++k) ss = ss + sq[k];
    const float denom = sqrtf(ss) + 1e-10f;
#pragma unroll
    for (int k = 0; k < K_DIM; ++k) a[k] = a[k] / denom;
}

__device__ __forceinline__ unsigned short bf16_bits(float f) {
    __hip_bfloat16 h = __float2bfloat16(f);   // RNE
    unsigned short u;
    __builtin_memcpy(&u, &h, 2);
    return u;
}
__device__ __forceinline__ float bf16_val(float f) {
    return __bfloat162float(__float2bfloat16(f));
}

// Kernel 1: np-exact cmat normalize -> bnT rows (refine) + hi/lo MFMA
// B-fragments (B1 hi, B2 lo; layout verified R8); zero wl counter.
__global__ __launch_bounds__(256) void prep_b(
    const float* __restrict__ cmat, float* __restrict__ bnT,
    unsigned short* __restrict__ B1, int* __restrict__ wl_count) {
#pragma clang fp contract(off)
    if (blockIdx.x == 0 && threadIdx.x == 0) *wl_count = 0;
    const int d = blockIdx.x * 256 + threadIdx.x;   // grid = 4 * 256
    if (d >= D_BINS) return;

    float t[K_DIM];
    norm_np(cmat, D_BINS, d, t);

    unsigned short* B2 = B1 + 16384;   // +32 KB
    const int tile = d >> 4, n = d & 15;
#pragma unroll
    for (int k = 0; k < K_DIM; ++k) {
        bnT[d * K_DIM + k] = t[k];
        const float hi_f = bf16_val(t[k]);
        const int idx = tile * 256 + ((k >> 3) * 16 + n) * 8 + (k & 7);
        B1[idx] = bf16_bits(t[k]);
        B2[idx] = bf16_bits(t[k] - hi_f);
    }
}

// Kernel 2: MFMA screen. Block = 512 thr (8 waves), B1|B2 staged in LDS.
// Wave owns 32 points (2 16-row tiles); 64 bin-tile iters; per tile:
//   acc = mfma(A, b_hi, C=2.0); acc = mfma(A, b_lo, acc)
//   => 2.0 + (a_hi+a_lo)·b_hi + a_hi·b_lo   (positive -> uint-sortable)
// Top-2 tracked as packed uint (score_bits & ~0x7FF) | (2047-d):
//   uint max == higher score, ties -> lower d (np first-max-wins).
__global__ __launch_bounds__(512) void mfma_screen(
    const float* __restrict__ x, const unsigned short* __restrict__ Bpack,
    int* __restrict__ out, int* __restrict__ wl, int* __restrict__ wl_count) {
#pragma clang fp contract(off)
    __shared__ float4 ldsB[4097];     // 64 KB tables + 16 B zero block

    // stage B1|B2 (64 KB) cooperatively
    {
        const float4* src = (const float4*)Bpack;
#pragma unroll
        for (int j = 0; j < 8; ++j)
            ldsB[threadIdx.x + j * 512] = src[threadIdx.x + j * 512];
        if (threadIdx.x == 0) ldsB[4096] = (float4){0.f, 0.f, 0.f, 0.f};
    }

    const int lane = threadIdx.x & 63;
    const int wv   = threadIdx.x >> 6;              // 0..7
    const int W    = blockIdx.x * 8 + wv;           // grid = 512 * 512
    const int P    = W * 32;
    const int m    = lane & 15;                     // bin column within tile
    const int q    = lane >> 4;                     // quad -> (k-chunk / point rows)

    // Build A fragments (2 tiles x 16 points): kp=(lane>>4)*8+j,
    // kp<16 -> hi[kp], kp>=16 -> lo[kp-16].
    bf16x8 A[2];
#pragma unroll
    for (int t = 0; t < 2; ++t) {
        float a[K_DIM];
        norm_np(x, N_PTS, P + t * 16 + m, a);
        unsigned short els[8];
#pragma unroll
        for (int j = 0; j < 8; ++j) {
            const int k = (q & 1) * 8 + j;
            if (q < 2) els[j] = bf16_bits(a[k]);
            else       els[j] = bf16_bits(a[k] - bf16_val(a[k]));
        }
        __builtin_memcpy(&A[t], els, 16);
    }

    __syncthreads();

    // LDS read pointers: B1 mirrored (lane&31); B2 zeroed for lanes>=32.
    const char* lb = (const char*)ldsB;
    const char* b1p = lb + (size_t)(lane & 31) * 16;
    const char* b2p = (lane < 32) ? (lb + 32768 + (size_t)lane * 16) : (lb + 65536);
    const int   b2s = (lane < 32) ? 512 : 0;

    unsigned ub1[2][4], ub2[2][4];
#pragma unroll
    for (int t = 0; t < 2; ++t)
#pragma unroll
        for (int r = 0; r < 4; ++r) { ub1[t][r] = 0u; ub2[t][r] = 0u; }

    const unsigned mask = 0xFFFFF800u;

    for (int i = 0; i < 64; ++i) {
        bf16x8 bf1, bf2;
        __builtin_memcpy(&bf1, b1p + (size_t)i * 512, 16);
        __builtin_memcpy(&bf2, b2p + (size_t)i * b2s, 16);

        f32x4 acc[2];
#pragma unroll
        for (int t = 0; t < 2; ++t)
            acc[t] = __builtin_amdgcn_mfma_f32_16x16x32_bf16(
                A[t], bf1, (f32x4){2.f, 2.f, 2.f, 2.f}, 0, 0, 0);
#pragma unroll
        for (int t = 0; t < 2; ++t)
            acc[t] = __builtin_amdgcn_mfma_f32_16x16x32_bf16(
                A[t], bf2, acc[t], 0, 0, 0);

        const unsigned dcomp = 2047u - (unsigned)(i * 16 + m);
#pragma unroll
        for (int t = 0; t < 2; ++t)
#pragma unroll
            for (int r = 0; r < 4; ++r) {
                const unsigned u = (__float_as_uint(acc[t][r]) & mask) | dcomp;
                const unsigned nx = max(ub1[t][r], u);
                ub2[t][r] = max(ub2[t][r], min(ub1[t][r], u));
                ub1[t][r] = nx;
            }
    }

    // merge top-2 across the 16 bin-columns (m) of each quad group
#pragma unroll
    for (int t = 0; t < 2; ++t)
#pragma unroll
        for (int r = 0; r < 4; ++r) {
            unsigned u1 = ub1[t][r], u2 = ub2[t][r];
#pragma unroll
            for (int s = 1; s <= 8; s <<= 1) {
                const unsigned o1 = (unsigned)__shfl_xor((int)u1, s, 16);
                const unsigned o2 = (unsigned)__shfl_xor((int)u2, s, 16);
                const unsigned n1 = max(u1, o1);
                u2 = max(min(u1, o1), max(u2, o2));
                u1 = n1;
            }
            if (m == 0) {
                const int p  = P + t * 16 + q * 4 + r;
                const float s1 = __uint_as_float(u1 & mask);
                const float s2 = __uint_as_float(u2 & mask);
                if (s1 - s2 > MARGIN_P) {
                    out[p] = 2047 - (int)(u1 & 2047u);
                } else {
                    const int pos = atomicAdd(wl_count, 1);
                    wl[pos] = p;
                }
            }
        }
}

// Kernel 3: np-exact rescan, one wave per worklisted point (proven R7/R8).
__global__ __launch_bounds__(256) void ncc_exact_refine(
    const float* __restrict__ x, const float* __restrict__ bnT,
    int* __restrict__ out, const int* __restrict__ wl,
    const int* __restrict__ wl_count) {
#pragma clang fp contract(off)
    const int count  = *wl_count;
    const int lane   = threadIdx.x & 63;
    const int wave   = (blockIdx.x * 256 + threadIdx.x) >> 6;
    const int nwaves = (gridDim.x * 256) >> 6;

    for (int i = wave; i < count; i += nwaves) {
        const int n = wl[i];
        float a[K_DIM];
        norm_np(x, N_PTS, n, a);

        float best = -3.402823466e38f;
        int   idx  = 0x7fffffff;
        const float4* b4 = (const float4*)bnT;
        for (int t = 0; t < 16; ++t) {
            const int d = t * 64 + lane;
            const float4 q0 = b4[d * 4 + 0];
            const float4 q1 = b4[d * 4 + 1];
            const float4 q2 = b4[d * 4 + 2];
            const float4 q3 = b4[d * 4 + 3];
            float sc;
            sc = a[0] * q0.x;
            sc = sc + a[1]  * q0.y; sc = sc + a[2]  * q0.z; sc = sc + a[3]  * q0.w;
            sc = sc + a[4]  * q1.x; sc = sc + a[5]  * q1.y; sc = sc + a[6]  * q1.z;
            sc = sc + a[7]  * q1.w; sc = sc + a[8]  * q2.x; sc = sc + a[9]  * q2.y;
            sc = sc + a[10] * q2.z; sc = sc + a[11] * q2.w; sc = sc + a[12] * q3.x;
            sc = sc + a[13] * q3.y; sc = sc + a[14] * q3.z; sc = sc + a[15] * q3.w;
            if (sc > best) { best = sc; idx = d; }
        }
#pragma unroll
        for (int mk = 1; mk <= 32; mk <<= 1) {
            const float ob = __shfl_xor(best, mk);
            const int   oi = __shfl_xor(idx,  mk);
            if (ob > best || (ob == best && oi < idx)) { best = ob; idx = oi; }
        }
        if (lane == 0) out[n] = idx;
    }
}

// Fallback (small ws): proven-exact full scan (R4).
__global__ __launch_bounds__(256) void ncc_argmax_np32(
    const float* __restrict__ x, const float* __restrict__ bnT,
    int* __restrict__ out) {
#pragma clang fp contract(off)
    const int n = blockIdx.x * 256 + threadIdx.x;
    float a[K_DIM];
    norm_np(x, N_PTS, n, a);

    float best = -3.402823466e38f;
    int   idx  = 0;
    const float4* b4 = (const float4*)bnT;
#pragma unroll 2
    for (int d = 0; d < D_BINS; ++d) {
        const float4 q0 = b4[d * 4 + 0];
        const float4 q1 = b4[d * 4 + 1];
        const float4 q2 = b4[d * 4 + 2];
        const float4 q3 = b4[d * 4 + 3];
        float sc;
        sc = a[0] * q0.x;
        sc = sc + a[1]  * q0.y; sc = sc + a[2]  * q0.z; sc = sc + a[3]  * q0.w;
        sc = sc + a[4]  * q1.x; sc = sc + a[5]  * q1.y; sc = sc + a[6]  * q1.z;
        sc = sc + a[7]  * q1.w; sc = sc + a[8]  * q2.x; sc = sc + a[9]  * q2.y;
        sc = sc + a[10] * q2.z; sc = sc + a[11] * q2.w; sc = sc + a[12] * q3.x;
        sc = sc + a[13] * q3.y; sc = sc + a[14] * q3.z; sc = sc + a[15] * q3.w;
        if (sc > best) { best = sc; idx = d; }
    }
    out[n] = idx;
}

__global__ __launch_bounds__(256) void normalize_rows_only(
    const float* __restrict__ cmat, float* __restrict__ bnT) {
#pragma clang fp contract(off)
    const int d = blockIdx.x * 256 + threadIdx.x;
    if (d >= D_BINS) return;
    float t[K_DIM];
    norm_np(cmat, D_BINS, d, t);
#pragma unroll
    for (int k = 0; k < K_DIM; ++k) bnT[d * K_DIM + k] = t[k];
}

extern "C" void kernel_launch(void* const* d_in, const int* in_sizes, int n_in,
                              void* d_out, int out_size, void* d_ws, size_t ws_size,
                              hipStream_t stream) {
    const float* x    = (const float*)d_in[0];   // [1, 16, 131072] fp32
    const float* cmat = (const float*)d_in[1];   // [16, 1024] fp32
    int* out = (int*)d_out;                      // [1, 131072] int32
    char* ws = (char*)d_ws;

    if (ws_size >= (size_t)WS_NEED) {
        int*            wl_count = (int*)ws;
        float*          bnT      = (float*)(ws + WS_OFF_BN);
        unsigned short* Bpack    = (unsigned short*)(ws + WS_OFF_B);
        int*            wl       = (int*)(ws + WS_OFF_WL);

        prep_b<<<4, 256, 0, stream>>>(cmat, bnT, Bpack, wl_count);
        mfma_screen<<<512, 512, 0, stream>>>(x, Bpack, out, wl, wl_count);
        ncc_exact_refine<<<512, 256, 0, stream>>>(x, bnT, out, wl, wl_count);
    } else {
        float* bnT = (float*)(ws + WS_OFF_BN);
        normalize_rows_only<<<4, 256, 0, stream>>>(cmat, bnT);
        ncc_argmax_np32<<<512, 256, 0, stream>>>(x, bnT, out);
    }
}